// Round 1
// 518.845 us; speedup vs baseline: 1.2321x; 1.2321x over previous
//
#include <hip/hip_runtime.h>

#define BB 256
#define TT 2048
#define II 128
#define HH 128
#define GS 16              // steps per group
#define NG (TT / GS)       // 128 groups

typedef __attribute__((ext_vector_type(8))) short short8;  // 8 bf16 (4 VGPR)
typedef __attribute__((ext_vector_type(4))) float f32x4;   // MFMA C/D

// Light per-step barrier: drain LDS ops then barrier in ONE asm block
// (vmcnt NOT drained — x-prefetch loads / out-stores fly across steps).
__device__ __forceinline__ void step_barrier() {
    asm volatile("s_waitcnt lgkmcnt(0)\n\ts_barrier" ::: "memory");
}

__device__ __forceinline__ float tanh_fast(float s) {
    // tanh(s) = 1 - 2/(e^{2s}+1); e^{2s} = 2^(s * 2/ln2), one v_exp_f32.
    // Saturates correctly: s>>0 -> exp2=inf -> rcp=0 -> 1; s<<0 -> -1.
#if __has_builtin(__builtin_amdgcn_exp2f)
    const float e = __builtin_amdgcn_exp2f(s * 2.8853900817779268f);
#else
    const float e = exp2f(s * 2.8853900817779268f);
#endif
    return 1.0f - 2.0f * __builtin_amdgcn_rcpf(e + 1.0f);
}

// float -> bf16 round-to-nearest-even
__device__ __forceinline__ unsigned int f2bf(float f) {
    unsigned int u = __float_as_uint(f);
    u += 0x7FFF + ((u >> 16) & 1);
    return u >> 16;
}
__device__ __forceinline__ unsigned int pack2(float lo, float hi) {
    return f2bf(lo) | (f2bf(hi) << 16);
}

// R14: latency-bound on the serial step (R13 measured ~750 cyc/step).
// Three critical-path cuts vs R13:
//  (1) Break the 4-deep MFMA C-chain: 8 INDEPENDENT accumulators (one per
//      kf x n-tile), summed with a 2-level f32 add tree. MFMA dependent
//      latency ~20-40c each, so chain 4x -> 1x saves ~60-120c/step.
//  (2) ax prefetch: axbuf[g][w+1] is valid a full group ahead; read it into
//      registers DURING step w (hidden under MFMA wait) instead of after
//      the barrier of step w+1.
//  (3) Permuted hA k-layout: slot 32q+2c holds col 32q+c, slot 32q+2c+1
//      holds col 32q+16+c. The W_hh fragments gather the SAME permutation
//      of the contraction index at setup (pure relabeling, exact). Each
//      h-wave lane's two outputs are then adjacent -> ONE ds_write_b32
//      instead of two ds_write_b16.
// x-projection path: R12/R13 MFMA path verbatim (4 waves). 512 thr = 8 waves.
__launch_bounds__(512, 1)
__global__ void rnn_pipe(const float* __restrict__ x,
                         const float* __restrict__ w_ih,
                         const float* __restrict__ w_hh,
                         const float* __restrict__ b_ih,
                         const float* __restrict__ b_hh,
                         float* __restrict__ out) {
    const int b    = blockIdx.x;
    const int tid  = threadIdx.x;
    const int wave = tid >> 6;
    const int lane = tid & 63;
    const bool hw  = (wave < 4);

    __shared__ __align__(16) unsigned short hA[2][HH];           // bf16 h ping-pong (k-permuted)
    __shared__ __align__(16) float axbuf[2][GS][HH];             // 16 KB
    __shared__ __align__(16) unsigned short xstage[2][4][64][8]; // 8 KB bf16 A-frags

    const float* xb = x + (size_t)b * (TT * II);

    // ---------------- h-wave setup: W_hh B-frags (bf16, k-permuted) ----------------
    const int jb_h = (wave & 3) * 32;    // h-wave owns cols [jb_h, jb_h+32)
    short8 WH[2][4];
    if (hw) {
#pragma unroll
        for (int nt = 0; nt < 2; ++nt) {
            const int jj = jb_h + nt * 16 + (lane & 15);
#pragma unroll
            for (int kf = 0; kf < 4; ++kf) {
                short8 s;
#pragma unroll
                for (int e = 0; e < 8; ++e) {
                    const int kp = kf * 32 + (lane >> 4) * 8 + e;  // A-slot index
                    const int m  = kp & 31;
                    // slot -> original k: 32a+2c -> 32a+c ; 32a+2c+1 -> 32a+16+c
                    const int ko = (kp & ~31) + (m >> 1) + ((m & 1) << 4);
                    s[e] = (short)f2bf(w_hh[(size_t)jj * HH + ko]);
                }
                WH[nt][kf] = s;
            }
        }
    }

    // ---------------- x-wave setup (R12 verbatim, q rebased) ----------------
    const int xwq = wave - 4;        // 0..3
    const int jb  = xwq * 32;        // owns j in [jb, jb+32): 2 N-tiles
    short8 WF[2][4];
    float biasv[2];
    const int q   = tid - 256;       // 0..255 for x-threads
    const int t_s = q >> 4;          // 0..15
    const int m   = q & 15;
    const int i0  = m * 8;
    const int kfs = m >> 2;                  // k-frag of this chunk
    const int lps = (m & 3) * 16 + t_s;      // A-frag lane slot
    if (!hw) {
#pragma unroll
        for (int nt = 0; nt < 2; ++nt) {
            const int jj = jb + nt * 16 + (lane & 15);
            biasv[nt] = b_ih[jj] + b_hh[jj];
#pragma unroll
            for (int kf = 0; kf < 4; ++kf) {
                const float* wp = w_ih + (size_t)jj * II + kf * 32 + (lane >> 4) * 8;
                short8 s;
#pragma unroll
                for (int e = 0; e < 8; ++e) s[e] = (short)f2bf(wp[e]);
                WF[nt][kf] = s;
            }
        }
    }

#define STAGE_X(BUF, R0, R1) do { \
        uint4 P_; P_.x = pack2((R0).x, (R0).y); P_.y = pack2((R0).z, (R0).w); \
        P_.z = pack2((R1).x, (R1).y); P_.w = pack2((R1).z, (R1).w); \
        *reinterpret_cast<uint4*>(&xstage[BUF][kfs][lps][0]) = P_; } while (0)

#define XPROJ(SB, AB) do { \
        const short8 A0 = *reinterpret_cast<const short8*>(&xstage[SB][0][lane][0]); \
        const short8 A1 = *reinterpret_cast<const short8*>(&xstage[SB][1][lane][0]); \
        const short8 A2 = *reinterpret_cast<const short8*>(&xstage[SB][2][lane][0]); \
        const short8 A3 = *reinterpret_cast<const short8*>(&xstage[SB][3][lane][0]); \
        f32x4 ac0 = {0.f, 0.f, 0.f, 0.f}, ac1 = {0.f, 0.f, 0.f, 0.f}; \
        ac0 = __builtin_amdgcn_mfma_f32_16x16x32_bf16(A0, WF[0][0], ac0, 0, 0, 0); \
        ac0 = __builtin_amdgcn_mfma_f32_16x16x32_bf16(A1, WF[0][1], ac0, 0, 0, 0); \
        ac0 = __builtin_amdgcn_mfma_f32_16x16x32_bf16(A2, WF[0][2], ac0, 0, 0, 0); \
        ac0 = __builtin_amdgcn_mfma_f32_16x16x32_bf16(A3, WF[0][3], ac0, 0, 0, 0); \
        ac1 = __builtin_amdgcn_mfma_f32_16x16x32_bf16(A0, WF[1][0], ac1, 0, 0, 0); \
        ac1 = __builtin_amdgcn_mfma_f32_16x16x32_bf16(A1, WF[1][1], ac1, 0, 0, 0); \
        ac1 = __builtin_amdgcn_mfma_f32_16x16x32_bf16(A2, WF[1][2], ac1, 0, 0, 0); \
        ac1 = __builtin_amdgcn_mfma_f32_16x16x32_bf16(A3, WF[1][3], ac1, 0, 0, 0); \
        const int c_ = lane & 15, rb_ = (lane >> 4) * 4; \
        _Pragma("unroll") \
        for (int r = 0; r < 4; ++r) { \
            axbuf[AB][rb_ + r][jb + c_]      = ac0[r] + biasv[0]; \
            axbuf[AB][rb_ + r][jb + 16 + c_] = ac1[r] + biasv[1]; \
        } } while (0)

    // ---------------- prologue ----------------
    float4 nr0, nr1;
    if (!hw) {
        float4 p0 = *reinterpret_cast<const float4*>(&xb[t_s * II + i0]);
        float4 p1 = *reinterpret_cast<const float4*>(&xb[t_s * II + i0 + 4]);
        STAGE_X(1, p0, p1);
        nr0 = *reinterpret_cast<const float4*>(&xb[(GS + t_s) * II + i0]);
        nr1 = *reinterpret_cast<const float4*>(&xb[(GS + t_s) * II + i0 + 4]);
    }
    if (tid < HH) hA[0][tid] = 0;          // bf16 zero (permutation-invariant)
    __syncthreads();
    if (!hw) {
        XPROJ(1, 0);             // axbuf[0] (group 0)
        STAGE_X(0, nr0, nr1);    // xstage[0] <- x of group 1
    }
    __syncthreads();

    // ax prefetch registers (h-waves): ax for the step ABOUT to run
    float axn0 = 0.f, axn1 = 0.f;
    if (hw) {
        axn0 = axbuf[0][0][jb_h + (lane & 15)];
        axn1 = axbuf[0][0][jb_h + 16 + (lane & 15)];
    }

    // ---------------- main loop ----------------
    for (int g = 0; g < NG; ++g) {
#pragma unroll
        for (int w = 0; w < GS; ++w) {
            if (hw) {
                const int p  = w & 1;
                const int ko = (lane >> 4) * 8;
                // A = h broadcast into all 16 rows (permuted k-layout matches WH)
                const short8 A0 = *reinterpret_cast<const short8*>(&hA[p][ 0 + ko]);
                const short8 A1 = *reinterpret_cast<const short8*>(&hA[p][32 + ko]);
                const short8 A2 = *reinterpret_cast<const short8*>(&hA[p][64 + ko]);
                const short8 A3 = *reinterpret_cast<const short8*>(&hA[p][96 + ko]);
                // 8 INDEPENDENT accumulators: no MFMA C-chain on the critical path
                f32x4 a0 = {0.f,0.f,0.f,0.f}, a1 = {0.f,0.f,0.f,0.f};
                f32x4 a2 = {0.f,0.f,0.f,0.f}, a3 = {0.f,0.f,0.f,0.f};
                f32x4 c0 = {0.f,0.f,0.f,0.f}, c1 = {0.f,0.f,0.f,0.f};
                f32x4 c2 = {0.f,0.f,0.f,0.f}, c3 = {0.f,0.f,0.f,0.f};
                a0 = __builtin_amdgcn_mfma_f32_16x16x32_bf16(A0, WH[0][0], a0, 0, 0, 0);
                a1 = __builtin_amdgcn_mfma_f32_16x16x32_bf16(A1, WH[0][1], a1, 0, 0, 0);
                a2 = __builtin_amdgcn_mfma_f32_16x16x32_bf16(A2, WH[0][2], a2, 0, 0, 0);
                a3 = __builtin_amdgcn_mfma_f32_16x16x32_bf16(A3, WH[0][3], a3, 0, 0, 0);
                c0 = __builtin_amdgcn_mfma_f32_16x16x32_bf16(A0, WH[1][0], c0, 0, 0, 0);
                c1 = __builtin_amdgcn_mfma_f32_16x16x32_bf16(A1, WH[1][1], c1, 0, 0, 0);
                c2 = __builtin_amdgcn_mfma_f32_16x16x32_bf16(A2, WH[1][2], c2, 0, 0, 0);
                c3 = __builtin_amdgcn_mfma_f32_16x16x32_bf16(A3, WH[1][3], c3, 0, 0, 0);
                // consume current-step ax, then prefetch next step's (hidden
                // under MFMA completion; buffer is valid a full group ahead)
                const float axv0 = axn0, axv1 = axn1;
                {
                    const int wn  = (w + 1) & (GS - 1);
                    const int gnb = (w == GS - 1) ? ((g + 1) & 1) : (g & 1);
                    axn0 = axbuf[gnb][wn][jb_h + (lane & 15)];
                    axn1 = axbuf[gnb][wn][jb_h + 16 + (lane & 15)];
                }
                // 2-level add tree (every lane holds col (lane&15) redundantly)
                const float s0 = (a0[0] + a1[0]) + (a2[0] + a3[0]) + axv0;
                const float s1 = (c0[0] + c1[0]) + (c2[0] + c3[0]) + axv1;
                const float hn0 = tanh_fast(s0);
                const float hn1 = tanh_fast(s1);
                if (lane < 16) {
                    // permuted layout: cols (jb_h+lane, jb_h+16+lane) are
                    // adjacent slots -> ONE packed dword write
                    *reinterpret_cast<unsigned int*>(&hA[p ^ 1][jb_h + 2 * lane])
                        = pack2(hn0, hn1);
                    float* ob = out + (size_t)b * (TT * HH)
                              + (size_t)(g * GS + w) * HH + jb_h + lane;
                    ob[0]  = hn0;     // fire-and-forget; no vmcnt wait in loop
                    ob[16] = hn1;
                }
            } else {
                if (w == 0 && g + 1 < NG) {
                    XPROJ(g & 1, (g + 1) & 1);   // ax for group g+1
                }
                if (w == 1 && g + 2 < NG) {
                    const int tb = (g + 2) * GS;
                    nr0 = *reinterpret_cast<const float4*>(&xb[(size_t)(tb + t_s) * II + i0]);
                    nr1 = *reinterpret_cast<const float4*>(&xb[(size_t)(tb + t_s) * II + i0 + 4]);
                }
                if (w == 8 && g + 2 < NG) {
                    STAGE_X((g + 1) & 1, nr0, nr1);   // x of group g+2
                }
            }
            step_barrier();
        }
    }
#undef XPROJ
#undef STAGE_X
}

extern "C" void kernel_launch(void* const* d_in, const int* in_sizes, int n_in,
                              void* d_out, int out_size, void* d_ws, size_t ws_size,
                              hipStream_t stream) {
    const float* x    = (const float*)d_in[0];
    const float* w_ih = (const float*)d_in[1];
    const float* w_hh = (const float*)d_in[2];
    const float* b_ih = (const float*)d_in[3];
    const float* b_hh = (const float*)d_in[4];
    float* out = (float*)d_out;

    rnn_pipe<<<BB, 512, 0, stream>>>(x, w_ih, w_hh, b_ih, b_hh, out);
}